// Round 16
// baseline (1591.363 us; speedup 1.0000x reference)
//
#include <hip/hip_runtime.h>
#include <hip/hip_bf16.h>
#include <math.h>

// Problem constants
#define NTOK 1024          // Hp*Wp = 32*32
#define CDIM 768
#define BDIM 2
#define ROWS (BDIM*NTOK)   // 2048
#define NHEAD 12
#define HEADD 64
#define SCALE 0.125f       // 64^-0.5

typedef __attribute__((ext_vector_type(8))) __bf16 bfx8;
typedef __attribute__((ext_vector_type(4))) float f32x4;
typedef __attribute__((ext_vector_type(8))) unsigned short u16x8;
typedef __attribute__((ext_vector_type(4))) unsigned short u16x4;

__device__ __forceinline__ float us2f(unsigned short u) {
  return __uint_as_float(((unsigned int)u) << 16);
}
__device__ __forceinline__ unsigned short f2bfu(float v) {
  union { __bf16 b; unsigned short u; } c; c.b = (__bf16)v; return c.u;
}
// dtype-flexible scalar load at ELEMENT index i: isbf ? bf16[i] : f32[i]
__device__ __forceinline__ float ldP(const void* p, size_t i, bool isbf) {
  return isbf ? us2f(((const unsigned short*)p)[i]) : ((const float*)p)[i];
}
// split f32 -> bf16 hi + lo planes
__device__ __forceinline__ void stPlanes(float v, size_t idx,
                                         unsigned short* hp, unsigned short* lp) {
  unsigned short h = f2bfu(v);
  hp[idx] = h;
  lp[idx] = f2bfu(v - us2f(h));
}

__device__ __forceinline__ float waveSum(float v) {
#pragma unroll
  for (int off = 32; off; off >>= 1) v += __shfl_xor(v, off, 64);
  return v;
}

// ---------------------------------------------------------------- dtype detector
// bf16 buffer of 0.02-scale gaussians: ~256/256 halfwords have sane exponent.
// f32 buffer: only odd halfwords do (~152/256 expected). Threshold 220 (≈15σ).
__global__ void detect_kernel(const void* __restrict__ probe, int* __restrict__ flag) {
  const unsigned short* u = (const unsigned short*)probe;
  int plaus = 0;
  for (int i = 0; i < 256; i++) {
    int e = (u[i] >> 7) & 0xFF;
    if (e >= 0x60 && e <= 0x8F) plaus++;
  }
  *flag = (plaus >= 220) ? 1 : 0;
}

// ---------------------------------------------------------------- im2col (plane output)
__global__ __launch_bounds__(256) void im2col_kernel(const void* __restrict__ x,
                                                     float* __restrict__ col,
                                                     const int* __restrict__ dt) {
  bool isbf = (*dt != 0);
  int idx = blockIdx.x * 256 + threadIdx.x;     // < 2048*768
  int k = idx % 768;
  int row = idx / 768;
  int n = row & (NTOK - 1);
  int b = row >> 10;
  int ci = k >> 8;
  int rem = k & 255;
  int py = rem >> 4, px = rem & 15;
  int hp = n >> 5, wp = n & 31;
  int iy = hp * 16 + py, ix = wp * 16 + px;
  size_t xi = (((size_t)(b * 3 + ci) * 512) + iy) * 512 + ix;
  float v = ldP(x, xi, isbf);
  unsigned short* colH = (unsigned short*)col;
  unsigned short* colL = colH + (size_t)ROWS * CDIM;
  stPlanes(v, idx, colH, colL);
}

// ---------------------------------------------------------------- GEMM (MFMA, both dtypes)
// Y[m,n](ldy) (+)= A[m,k] @ W[wOff + n, k]^T + bias[bOff + n]
// A given as bf16 hi/lo planes (AH base; AL = AH + ROWS*lda elems).
// LDS = 24KB (residency 6 blocks/CU vs 3 at 48KB -- the barrier-drain stall is
// hidden only by co-resident block overlap, m114):
//   isbf: BK=64, single product (ah*w). AH@0(16K), W@16K(8K). Row stride 128B
//         = bank period -> per-row unit swizzle phys = u ^ (row&7),
//         pre-applied on the global source; staging writes linear (tid*16).
//   else: BK=32, 3 products (r7-verified layout). AH@0(8K: row m at m*64)
//         AL@8K WH@16K(4K) WL@20K(4K). Swizzle u ^ ((row>>1)&3).
//         Fragment reads: mf=1 is +16 rows = +1024 BYTES (r15 bug was +4096).
// XCD-chunked bijective block swizzle, two orientations (bit4 W-stationary).
// Split-K via gridDim.z -> f32 partials (raw, no bias/act).
// flags: bit0 residual add, bit1 exact GELU, bit2 plane output,
//        bit3 write q hi/lo planes (n<768) to Ypart, bit4 W-stationary
__global__ __launch_bounds__(256) void gemm_kernel(
    const unsigned short* __restrict__ Aplanes, int lda,
    const void* __restrict__ Wraw, size_t wOff,
    const void* __restrict__ bias, size_t bOff,
    void* __restrict__ Yreg, int ldy,
    int Nout, int K, int flags, const int* __restrict__ dt,
    float* __restrict__ Ypart) {
  bool isbf = (*dt != 0);
  __shared__ __align__(16) unsigned char sm[24576];
  int tid = threadIdx.x;
  // XCD-chunked bijective swizzle (m204)
  int nwg = gridDim.x * gridDim.y;
  int orig = blockIdx.x + gridDim.x * blockIdx.y;
  int qq = nwg >> 3, rr = nwg & 7;
  int xcd = orig & 7, loc = orig >> 3;
  int wgid = (xcd < rr ? xcd * (qq + 1) : rr * (qq + 1) + (xcd - rr) * qq) + loc;
  int nbase, mbase;
  if (flags & 16) {                       // W-stationary: m-fastest in chunk
    mbase = (wgid % gridDim.y) * 128;
    nbase = (wgid / gridDim.y) * 64;
  } else {                                // A-stationary: n-fastest in chunk
    nbase = (wgid % gridDim.x) * 64;
    mbase = (wgid / gridDim.x) * 128;
  }
  // split-K range
  int KS = K / gridDim.z;
  int kb = blockIdx.z * KS;

  int lane = tid & 63, w = tid >> 6;
  int lr = lane & 15, lg = lane >> 4;

  const unsigned short* AH = Aplanes;
  const unsigned short* AL = AH + (size_t)ROWS * lda;
  int wr = tid * 16;                             // linear LDS write base

  f32x4 acc[2][4];
#pragma unroll
  for (int i = 0; i < 2; i++)
#pragma unroll
    for (int j = 0; j < 4; j++) acc[i][j] = f32x4{0.f, 0.f, 0.f, 0.f};

  if (isbf) {
    // ---- BK=64 single-product path: AH@0(16K), W@16K(8K)
    int r0 = tid >> 3;
    int lu = (tid & 7) ^ (r0 & 7);               // pre-swizzled global 16B unit
    size_t gA = (size_t)(mbase + r0) * lda + lu * 8;
    size_t aStep = (size_t)32 * lda;
    int wrow0 = nbase + r0;      if (wrow0 > Nout - 1) wrow0 = Nout - 1;
    int wrow1 = nbase + r0 + 32; if (wrow1 > Nout - 1) wrow1 = Nout - 1;
    size_t gW0 = (size_t)wrow0 * K + lu * 8;
    size_t gW1 = (size_t)wrow1 * K + lu * 8;
    int px0 = (lg ^ (lr & 7)) * 16;              // frag unit bytes, k-slice 0
    int px1 = ((4 | lg) ^ (lr & 7)) * 16;        // k-slice 1
    int rbA = (w * 32 + lr) * 128;               // A byte row offset

    const unsigned short* Wb = (const unsigned short*)Wraw + wOff;
    u16x8 rAh[4], rW0v, rW1v;
#pragma unroll
    for (int p = 0; p < 4; p++)
      rAh[p] = *(const u16x8*)(AH + gA + p * aStep + kb);
    rW0v = *(const u16x8*)(Wb + gW0 + kb);
    rW1v = *(const u16x8*)(Wb + gW1 + kb);
    for (int k0 = kb; k0 < kb + KS; k0 += 64) {
      __syncthreads();
#pragma unroll
      for (int p = 0; p < 4; p++)
        *(u16x8*)(sm + p * 4096 + wr) = rAh[p];
      *(u16x8*)(sm + 16384 + wr) = rW0v;
      *(u16x8*)(sm + 20480 + wr) = rW1v;
      __syncthreads();
      int k1 = k0 + 64;
      if (k1 < kb + KS) {
#pragma unroll
        for (int p = 0; p < 4; p++)
          rAh[p] = *(const u16x8*)(AH + gA + p * aStep + k1);
        rW0v = *(const u16x8*)(Wb + gW0 + k1);
        rW1v = *(const u16x8*)(Wb + gW1 + k1);
      }
#pragma unroll
      for (int s = 0; s < 2; s++) {
        int px = s ? px1 : px0;
        bfx8 ah0 = *(const bfx8*)(sm + rbA + px);
        bfx8 ah1 = *(const bfx8*)(sm + rbA + 2048 + px);
#pragma unroll
        for (int nf = 0; nf < 4; nf++) {
          bfx8 wh = *(const bfx8*)(sm + 16384 + (nf * 16 + lr) * 128 + px);
          acc[0][nf] = __builtin_amdgcn_mfma_f32_16x16x32_bf16(ah0, wh, acc[0][nf], 0, 0, 0);
          acc[1][nf] = __builtin_amdgcn_mfma_f32_16x16x32_bf16(ah1, wh, acc[1][nf], 0, 0, 0);
        }
      }
    }
  } else {
    // ---- BK=32 3-product path (r7-verified 24KB layout)
    int srow = tid >> 2;
    int swz = (tid & 3) ^ ((srow >> 1) & 3);
    size_t gA0 = (size_t)(mbase + srow) * lda + swz * 8;
    size_t gA1 = gA0 + (size_t)64 * lda;
    int gn = nbase + srow; if (gn > Nout - 1) gn = Nout - 1;
    size_t gW = (size_t)gn * K + swz * 8;
    int ub = (lg ^ ((lr >> 1) & 3)) * 16;
    int rmA = (w * 32 + lr) * 64;

    const float* Wf = (const float*)Wraw + wOff;
    u16x8 rA0h, rA1h, rA0l, rA1l;
    float4 rW0, rW1;
    rA0h = *(const u16x8*)(AH + gA0 + kb);
    rA1h = *(const u16x8*)(AH + gA1 + kb);
    rA0l = *(const u16x8*)(AL + gA0 + kb);
    rA1l = *(const u16x8*)(AL + gA1 + kb);
    rW0 = *(const float4*)(Wf + gW + kb);
    rW1 = *(const float4*)(Wf + gW + kb + 4);
    for (int k0 = kb; k0 < kb + KS; k0 += 32) {
      __syncthreads();
      *(u16x8*)(sm + wr) = rA0h;               // rows 0-63 hi  @ [0,4096)
      *(u16x8*)(sm + 4096 + wr) = rA1h;        // rows 64-127 hi @ [4096,8192)
      *(u16x8*)(sm + 8192 + wr) = rA0l;        // rows 0-63 lo
      *(u16x8*)(sm + 12288 + wr) = rA1l;       // rows 64-127 lo
      {
        float wv[8] = {rW0.x, rW0.y, rW0.z, rW0.w, rW1.x, rW1.y, rW1.z, rW1.w};
        u16x8 wh8, wl8;
#pragma unroll
        for (int i = 0; i < 8; i++) {
          unsigned short h = f2bfu(wv[i]);
          wh8[i] = h;
          wl8[i] = f2bfu(wv[i] - us2f(h));
        }
        *(u16x8*)(sm + 16384 + wr) = wh8;
        *(u16x8*)(sm + 20480 + wr) = wl8;
      }
      __syncthreads();
      int k1 = k0 + 32;
      if (k1 < kb + KS) {
        rA0h = *(const u16x8*)(AH + gA0 + k1);
        rA1h = *(const u16x8*)(AH + gA1 + k1);
        rA0l = *(const u16x8*)(AL + gA0 + k1);
        rA1l = *(const u16x8*)(AL + gA1 + k1);
        rW0 = *(const float4*)(Wf + gW + k1);
        rW1 = *(const float4*)(Wf + gW + k1 + 4);
      }
      // fragment reads: row m at byte m*64 (contiguous across 0..127);
      // mf=1 is +16 rows = +1024 bytes (r15 bug: was +4096)
      bfx8 ah0 = *(const bfx8*)(sm + rmA + ub);
      bfx8 ah1 = *(const bfx8*)(sm + rmA + 1024 + ub);
      bfx8 al0 = *(const bfx8*)(sm + 8192 + rmA + ub);
      bfx8 al1 = *(const bfx8*)(sm + 8192 + rmA + 1024 + ub);
#pragma unroll
      for (int nf = 0; nf < 4; nf++) {
        int rn = (nf * 16 + lr) * 64 + ub;
        bfx8 wh = *(const bfx8*)(sm + 16384 + rn);
        bfx8 wl = *(const bfx8*)(sm + 20480 + rn);
        acc[0][nf] = __builtin_amdgcn_mfma_f32_16x16x32_bf16(ah0, wh, acc[0][nf], 0, 0, 0);
        acc[0][nf] = __builtin_amdgcn_mfma_f32_16x16x32_bf16(al0, wh, acc[0][nf], 0, 0, 0);
        acc[0][nf] = __builtin_amdgcn_mfma_f32_16x16x32_bf16(ah0, wl, acc[0][nf], 0, 0, 0);
        acc[1][nf] = __builtin_amdgcn_mfma_f32_16x16x32_bf16(ah1, wh, acc[1][nf], 0, 0, 0);
        acc[1][nf] = __builtin_amdgcn_mfma_f32_16x16x32_bf16(al1, wh, acc[1][nf], 0, 0, 0);
        acc[1][nf] = __builtin_amdgcn_mfma_f32_16x16x32_bf16(ah1, wl, acc[1][nf], 0, 0, 0);
      }
    }
  }

  // ---- split-K partial epilogue: raw f32, no bias/act (reduce combines)
  if (gridDim.z > 1) {
    float* Pp = Ypart + (size_t)blockIdx.z * ((size_t)ROWS * ldy);
#pragma unroll
    for (int mf = 0; mf < 2; mf++)
#pragma unroll
      for (int nf = 0; nf < 4; nf++) {
        int n = nbase + nf * 16 + lr;
        if (n < Nout) {
#pragma unroll
          for (int r = 0; r < 4; r++) {
            int m = mbase + w * 32 + mf * 16 + lg * 4 + r;
            Pp[(size_t)m * ldy + n] = acc[mf][nf][r];
          }
        }
      }
    return;
  }

  // epilogue: D[row=(lane>>4)*4+r][col=lane&15] per 16x16 frag (verified layout)
  bool pOut = (flags & 4) != 0;
  bool qOut = (flags & 8) != 0;
  unsigned short* YH = (unsigned short*)Yreg;
  unsigned short* YL = YH + (size_t)ROWS * ldy;
  unsigned short* QH = (unsigned short*)Ypart;
  unsigned short* QL = QH + (size_t)ROWS * 768;
#pragma unroll
  for (int mf = 0; mf < 2; mf++) {
#pragma unroll
    for (int nf = 0; nf < 4; nf++) {
      int n = nbase + nf * 16 + lr;
      if (n < Nout) {
        float bv = bias ? ldP(bias, bOff + n, isbf) : 0.f;
#pragma unroll
        for (int r = 0; r < 4; r++) {
          int m = mbase + w * 32 + mf * 16 + lg * 4 + r;
          float v = acc[mf][nf][r] + bv;
          if (flags & 2) v = 0.5f * v * (1.0f + erff(v * 0.70710678118654752f));
          size_t yi = (size_t)m * ldy + n;
          if (pOut) {
            unsigned short h = f2bfu(v);
            YH[yi] = h;
            YL[yi] = f2bfu(v - us2f(h));
          } else {
            float* yp = (float*)Yreg + yi;
            if (flags & 1) v += *yp;
            *yp = v;
            if (qOut && n < 768) stPlanes(v, (size_t)m * 768 + n, QH, QL);
          }
        }
      }
    }
  }
}

// ---------------------------------------------------------------- split-K reduce for qkv
// QKVout[idx] = P0[idx] + P1[idx]  (in-place safe: QKVout == P0 base; each
// thread reads its own slots in [0,PS) and [PS,2PS) before writing [0,PS)).
// Optionally emits q hi/lo planes for cols < 768.
__global__ __launch_bounds__(256) void reduce_qkv_kernel(float* __restrict__ PART,
                                                         float* __restrict__ Qp) {
  size_t idx = (size_t)blockIdx.x * 256 + threadIdx.x;  // < ROWS*2304
  const size_t PS = (size_t)ROWS * 2304;
  float v = PART[idx] + PART[PS + idx];
  PART[idx] = v;
  if (Qp) {
    int col = (int)(idx % 2304);
    if (col < 768) {
      size_t row = idx / 2304;
      unsigned short* QH = (unsigned short*)Qp;
      unsigned short* QL = QH + (size_t)ROWS * 768;
      stPlanes(v, row * 768 + col, QH, QL);
    }
  }
}

// ---------------------------------------------------------------- split-K reduce (plain)
__global__ __launch_bounds__(256) void reduce_kernel(const float* __restrict__ PART,
                                                     int nsplit,
                                                     const void* __restrict__ bias,
                                                     size_t bOff,
                                                     float* __restrict__ X,
                                                     int resid,
                                                     const int* __restrict__ dt) {
  bool isbf = (*dt != 0);
  int idx = blockIdx.x * 256 + threadIdx.x;   // < 2048*768
  int n = idx % 768;
  float v = bias ? ldP(bias, bOff + n, isbf) : 0.f;
  const size_t XS = (size_t)ROWS * 768;
  for (int z = 0; z < nsplit; z++) v += PART[(size_t)z * XS + idx];
  X[idx] = resid ? (X[idx] + v) : v;
}

// ---------------------------------------------------------------- fused split-K reduce + residual + LayerNorm
__global__ __launch_bounds__(256) void reduce_ln_kernel(
    const float* __restrict__ PART, int nsplit,
    const void* __restrict__ bias, size_t bOff,
    float* __restrict__ X,
    const void* __restrict__ gs, const void* __restrict__ gb, size_t gOff,
    float* __restrict__ H, const int* __restrict__ dt) {
  bool isbf = (*dt != 0);
  int row = blockIdx.x;
  int tid = threadIdx.x;
  const size_t XS = (size_t)ROWS * 768;
  size_t rb = (size_t)row * CDIM;
  float v0, v1, v2;
  {
    float s0 = X[rb + tid]       + ldP(bias, bOff + tid, isbf);
    float s1 = X[rb + tid + 256] + ldP(bias, bOff + tid + 256, isbf);
    float s2 = X[rb + tid + 512] + ldP(bias, bOff + tid + 512, isbf);
    for (int z = 0; z < nsplit; z++) {
      const float* pz = PART + (size_t)z * XS + rb;
      s0 += pz[tid]; s1 += pz[tid + 256]; s2 += pz[tid + 512];
    }
    v0 = s0; v1 = s1; v2 = s2;
    X[rb + tid] = s0; X[rb + tid + 256] = s1; X[rb + tid + 512] = s2;
  }
  float sum = waveSum(v0 + v1 + v2);
  __shared__ float red[4];
  __shared__ float statMu;
  __shared__ float statRs;
  int wid = tid >> 6, lane = tid & 63;
  if (lane == 0) red[wid] = sum;
  __syncthreads();
  if (tid == 0) statMu = (red[0] + red[1] + red[2] + red[3]) * (1.0f / 768.0f);
  __syncthreads();
  float mu = statMu;
  float d0 = v0 - mu, d1 = v1 - mu, d2 = v2 - mu;
  float sq = waveSum(d0 * d0 + d1 * d1 + d2 * d2);
  if (lane == 0) red[wid] = sq;
  __syncthreads();
  if (tid == 0)
    statRs = rsqrtf((red[0] + red[1] + red[2] + red[3]) * (1.0f / 768.0f) + 1e-6f);
  __syncthreads();
  float rs = statRs;
  unsigned short* HH = (unsigned short*)H;
  unsigned short* HL = HH + (size_t)ROWS * CDIM;
  stPlanes(d0 * rs * ldP(gs, gOff + tid, isbf)       + ldP(gb, gOff + tid, isbf),       rb + tid, HH, HL);
  stPlanes(d1 * rs * ldP(gs, gOff + tid + 256, isbf) + ldP(gb, gOff + tid + 256, isbf), rb + tid + 256, HH, HL);
  stPlanes(d2 * rs * ldP(gs, gOff + tid + 512, isbf) + ldP(gb, gOff + tid + 512, isbf), rb + tid + 512, HH, HL);
}

// ---------------------------------------------------------------- LayerNorm (plane output)
__global__ __launch_bounds__(256) void ln_kernel(const float* __restrict__ X,
                                                 const void* __restrict__ gs,
                                                 const void* __restrict__ gb,
                                                 size_t gOff,
                                                 float* __restrict__ H,
                                                 const int* __restrict__ dt) {
  bool isbf = (*dt != 0);
  int row = blockIdx.x;
  int tid = threadIdx.x;
  const float* xr = X + (size_t)row * CDIM;
  float v0 = xr[tid], v1 = xr[tid + 256], v2 = xr[tid + 512];
  float sum = waveSum(v0 + v1 + v2);
  __shared__ float red[4];
  __shared__ float statMu;
  __shared__ float statRs;
  int wid = tid >> 6, lane = tid & 63;
  if (lane == 0) red[wid] = sum;
  __syncthreads();
  if (tid == 0) statMu = (red[0] + red[1] + red[2] + red[3]) * (1.0f / 768.0f);
  __syncthreads();
  float mu = statMu;
  float d0 = v0 - mu, d1 = v1 - mu, d2 = v2 - mu;
  float sq = waveSum(d0 * d0 + d1 * d1 + d2 * d2);
  if (lane == 0) red[wid] = sq;
  __syncthreads();
  if (tid == 0)
    statRs = rsqrtf((red[0] + red[1] + red[2] + red[3]) * (1.0f / 768.0f) + 1e-6f);
  __syncthreads();
  float rs = statRs;
  unsigned short* HH = (unsigned short*)H;
  unsigned short* HL = HH + (size_t)ROWS * CDIM;
  size_t rb = (size_t)row * CDIM;
  stPlanes(d0 * rs * ldP(gs, gOff + tid, isbf)       + ldP(gb, gOff + tid, isbf),       rb + tid, HH, HL);
  stPlanes(d1 * rs * ldP(gs, gOff + tid + 256, isbf) + ldP(gb, gOff + tid + 256, isbf), rb + tid + 256, HH, HL);
  stPlanes(d2 * rs * ldP(gs, gOff + tid + 512, isbf) + ldP(gb, gOff + tid + 512, isbf), rb + tid + 512, HH, HL);
}

// ---------------------------------------------------------------- deformable attention (plane output)
__global__ __launch_bounds__(256) void deform_kernel(const float* __restrict__ QKV,
                                                     const float* __restrict__ OFFS,
                                                     float* __restrict__ ATT) {
  int gid = blockIdx.x * 4 + (threadIdx.x >> 6);   // < 24576 = 2048*12
  int lane = threadIdx.x & 63;
  int h = gid % NHEAD;
  int bn = gid / NHEAD;          // b*1024 + n
  int n = bn & (NTOK - 1);
  int b = bn >> 10;
  int hp = n >> 5, wp = n & 31;

  float qd = QKV[(size_t)bn * 2304 + h * HEADD + lane];
  const float* orow = OFFS + (size_t)bn * 96 + h * 8;

  float sv[4], sc[4];
#pragma unroll
  for (int p = 0; p < 4; p++) {
    float ox = orow[p * 2 + 0];
    float oy = orow[p * 2 + 1];
    float xx = (float)wp + ox;
    float yy = (float)hp + oy;
    float x0f = floorf(xx), y0f = floorf(yy);
    int x0 = (int)x0f, y0 = (int)y0f;
    float wx = xx - x0f, wy = yy - y0f;
    int xs[2] = {x0, x0 + 1};
    int ys[2] = {y0, y0 + 1};
    float wxs[2] = {1.f - wx, wx};
    float wys[2] = {1.f - wy, wy};
    float skv = 0.f, svv = 0.f;
#pragma unroll
    for (int cy = 0; cy < 2; cy++) {
#pragma unroll
      for (int cx = 0; cx < 2; cx++) {
        int yi = ys[cy], xi = xs[cx];
        if (yi >= 0 && yi < 32 && xi >= 0 && xi < 32) {
          const float* kp = QKV + ((size_t)(b * NTOK + (yi << 5) + xi)) * 2304 + CDIM + h * HEADD + lane;
          float w = wys[cy] * wxs[cx];
          skv += w * kp[0];
          svv += w * kp[CDIM];
        }
      }
    }
    sv[p] = svv;
    sc[p] = waveSum(qd * skv) * SCALE;
  }
  float mx = fmaxf(fmaxf(sc[0], sc[1]), fmaxf(sc[2], sc[3]));
  float e0 = expf(sc[0] - mx), e1 = expf(sc[1] - mx), e2 = expf(sc[2] - mx), e3 = expf(sc[3] - mx);
  float l = e0 + e1 + e2 + e3;
  float od = (e0 * sv[0] + e1 * sv[1] + e2 * sv[2] + e3 * sv[3]) / l;
  unsigned short* AHp = (unsigned short*)ATT;
  unsigned short* ALp = AHp + (size_t)ROWS * CDIM;
  stPlanes(od, (size_t)bn * CDIM + h * HEADD + lane, AHp, ALp);
}

// ---------------------------------------------------------------- full attention (MFMA flash partial + combine)
__global__ __launch_bounds__(256) void flash_partial(const float* __restrict__ QKV,
                                                     float* __restrict__ PACC,
                                                     float* __restrict__ PM,
                                                     float* __restrict__ PL) {
  int bid = blockIdx.x;                 // ((b*12+h)*2 + kc)*16 + qb
  int qb = bid & 15;
  int kc = (bid >> 4) & 1;
  int bh = bid >> 5;                    // 0..23 = b*12 + h
  int h = bh % NHEAD;
  int b = bh / NHEAD;
  int tid = threadIdx.x;
  int lane = tid & 63, wq = tid >> 6;
  int lr = lane & 15, lg = lane >> 4;

  __shared__ __align__(16) unsigned short KH[64 * 72];
  __shared__ __align__(16) unsigned short KL[64 * 72];
  __shared__ __align__(16) unsigned short VTH[64 * 64];
  __shared__ __align__(16) unsigned short VTL[64 * 64];
  __shared__ __align__(16) unsigned short PH[4 * 16 * 64];
  __shared__ __align__(16) unsigned short PL_[4 * 16 * 64];

  const float* base = QKV + (size_t)b * NTOK * 2304;

  int qrow = qb * 64 + wq * 16 + lr;
  bfx8 qh[2], ql[2];
  {
    const float* qp = base + (size_t)qrow * 2304 + h * HEADD;
#pragma unroll
    for (int ks = 0; ks < 2; ks++) {
      float4 a0 = *(const float4*)(qp + ks * 32 + lg * 8);
      float4 a1 = *(const float4*)(qp + ks * 32 + lg * 8 + 4);
      float vv[8] = {a0.x, a0.y, a0.z, a0.w, a1.x, a1.y, a1.z, a1.w};
#pragma unroll
      for (int i = 0; i < 8; i++) {
        float sv = vv[i] * SCALE;
        __bf16 hh = (__bf16)sv;
        qh[ks][i] = hh;
        ql[ks][i] = (__bf16)(sv - (float)hh);
      }
    }
  }

  f32x4 oacc[4];
#pragma unroll
  for (int i = 0; i < 4; i++) oacc[i] = f32x4{0.f, 0.f, 0.f, 0.f};
  float mrun = -1e30f, l = 0.f;

  int srow = tid >> 2, su = tid & 3;
  const float* kgp = base + (size_t)srow * 2304 + CDIM + h * HEADD + su * 16;
  int vk = 4 * (tid & 15);
  int vd = 4 * (tid >> 4);

  float4 kr[4];
  float vrf[4][4];
  {
    int k0 = kc * 512;
#pragma unroll
    for (int c = 0; c < 4; c++)
      kr[c] = *(const float4*)(kgp + (size_t)k0 * 2304 + c * 4);
#pragma unroll
    for (int i = 0; i < 4; i++) {
      float4 t = *(const float4*)(base + (size_t)(k0 + vk + i) * 2304 + 2 * CDIM + h * HEADD + vd);
      vrf[i][0] = t.x; vrf[i][1] = t.y; vrf[i][2] = t.z; vrf[i][3] = t.w;
    }
  }

  for (int t = 0; t < 8; t++) {
    __syncthreads();
    {
      int e = srow * 72 + su * 16;
#pragma unroll
      for (int c2 = 0; c2 < 2; c2++) {
        float vv[8] = {kr[2 * c2].x, kr[2 * c2].y, kr[2 * c2].z, kr[2 * c2].w,
                       kr[2 * c2 + 1].x, kr[2 * c2 + 1].y, kr[2 * c2 + 1].z, kr[2 * c2 + 1].w};
        u16x8 hv, lv;
#pragma unroll
        for (int i = 0; i < 8; i++) {
          unsigned short hu = f2bfu(vv[i]);
          hv[i] = hu;
          lv[i] = f2bfu(vv[i] - us2f(hu));
        }
        *(u16x8*)&KH[e + c2 * 8] = hv;
        *(u16x8*)&KL[e + c2 * 8] = lv;
      }
    }
#pragma unroll
    for (int j = 0; j < 4; j++) {
      int d = vd + j;
      int off = d * 64 + (((vk >> 3) ^ (d & 7)) << 3) + (vk & 7);
      u16x4 hv, lv;
#pragma unroll
      for (int i = 0; i < 4; i++) {
        unsigned short hu = f2bfu(vrf[i][j]);
        hv[i] = hu;
        lv[i] = f2bfu(vrf[i][j] - us2f(hu));
      }
      *(u16x4*)&VTH[off] = hv;
      *(u16x4*)&VTL[off] = lv;
    }
    __syncthreads();
    if (t < 7) {
      int k0 = kc * 512 + (t + 1) * 64;
#pragma unroll
      for (int c = 0; c < 4; c++)
        kr[c] = *(const float4*)(kgp + (size_t)k0 * 2304 + c * 4);
#pragma unroll
      for (int i = 0; i < 4; i++) {
        float4 tv = *(const float4*)(base + (size_t)(k0 + vk + i) * 2304 + 2 * CDIM + h * HEADD + vd);
        vrf[i][0] = tv.x; vrf[i][1] = tv.y; vrf[i][2] = tv.z; vrf[i][3] = tv.w;
      }
    }

    f32x4 sAcc[4];
#pragma unroll
    for (int mf = 0; mf < 4; mf++) sAcc[mf] = f32x4{0.f, 0.f, 0.f, 0.f};
#pragma unroll
    for (int mf = 0; mf < 4; mf++) {
      int R = mf * 16 + lr;
#pragma unroll
      for (int ks = 0; ks < 2; ks++) {
        int e = R * 72 + (4 * ks + lg) * 8;
        bfx8 kh = *(const bfx8*)&KH[e];
        bfx8 kl = *(const bfx8*)&KL[e];
        sAcc[mf] = __builtin_amdgcn_mfma_f32_16x16x32_bf16(kh, qh[ks], sAcc[mf], 0, 0, 0);
        sAcc[mf] = __builtin_amdgcn_mfma_f32_16x16x32_bf16(kl, qh[ks], sAcc[mf], 0, 0, 0);
        sAcc[mf] = __builtin_amdgcn_mfma_f32_16x16x32_bf16(kh, ql[ks], sAcc[mf], 0, 0, 0);
      }
    }

    float pmax = sAcc[0][0];
#pragma unroll
    for (int mf = 0; mf < 4; mf++)
#pragma unroll
      for (int r = 0; r < 4; r++) pmax = fmaxf(pmax, sAcc[mf][r]);
    pmax = fmaxf(pmax, __shfl_xor(pmax, 16, 64));
    pmax = fmaxf(pmax, __shfl_xor(pmax, 32, 64));
    if (!__all(pmax - mrun <= 8.f)) {
      float mnew = fmaxf(mrun, pmax);
      float alpha = __expf(mrun - mnew);
      l *= alpha;
#pragma unroll
      for (int r = 0; r < 4; r++) {
        float ar = __shfl(alpha, 4 * lg + r, 64);
#pragma unroll
        for (int nf = 0; nf < 4; nf++) oacc[nf][r] *= ar;
      }
      mrun = mnew;
    }
    float p[4][4];
    float lsum = 0.f;
#pragma unroll
    for (int mf = 0; mf < 4; mf++)
#pragma unroll
      for (int r = 0; r < 4; r++) {
        float pv = __expf(sAcc[mf][r] - mrun);
        p[mf][r] = pv;
        lsum += pv;
      }
    lsum += __shfl_xor(lsum, 16, 64);
    lsum += __shfl_xor(lsum, 32, 64);
    l += lsum;

#pragma unroll
    for (int mf = 0; mf < 4; mf++) {
      int u = 2 * mf + (lg >> 1);
      int off = wq * 1024 + lr * 64 + ((u ^ (lr & 7)) << 3) + (lg & 1) * 4;
      u16x4 hv, lv;
#pragma unroll
      for (int r = 0; r < 4; r++) {
        unsigned short hu = f2bfu(p[mf][r]);
        hv[r] = hu;
        lv[r] = f2bfu(p[mf][r] - us2f(hu));
      }
      *(u16x4*)&PH[off] = hv;
      *(u16x4*)&PL_[off] = lv;
    }
    asm volatile("s_waitcnt lgkmcnt(0)" ::: "memory");
    __builtin_amdgcn_sched_barrier(0);

#pragma unroll
    for (int ks = 0; ks < 2; ks++) {
      int poff = wq * 1024 + lr * 64 + (((4 * ks + lg) ^ (lr & 7)) << 3);
      bfx8 pa_h = *(const bfx8*)&PH[poff];
      bfx8 pa_l = *(const bfx8*)&PL_[poff];
#pragma unroll
      for (int nf = 0; nf < 4; nf++) {
        int d = nf * 16 + lr;
        int voff = d * 64 + (((4 * ks + lg) ^ (d & 7)) << 3);
        bfx8 vb_h = *(const bfx8*)&VTH[voff];
        bfx8 vb_l = *(const bfx8*)&VTL[voff];
        oacc[nf] = __builtin_amdgcn_mfma_f32_16x16x32_bf16(pa_h, vb_h, oacc[nf], 0, 0, 0);
        oacc[nf] = __builtin_amdgcn_mfma_f32_16x16x32_bf16(pa_l, vb_h, oacc[nf], 0, 0, 0);
        oacc[nf] = __builtin_amdgcn_mfma_f32_16x16x32_bf16(pa_h, vb_l, oacc[nf], 0, 0, 0);
      }
    }
  }

  size_t idxbase = (size_t)(bh * 2 + kc) * NTOK;
  if (lane < 16) {
    PM[idxbase + qrow] = mrun;
    PL[idxbase + qrow] = l;
  }
#pragma unroll
  for (int r = 0; r < 4; r++) {
    int qg = qb * 64 + wq * 16 + 4 * lg + r;
    float* ap = PACC + (idxbase + qg) * 64;
#pragma unroll
    for (int nf = 0; nf < 4; nf++) ap[nf * 16 + lr] = oacc[nf][r];
  }
}

__global__ __launch_bounds__(256) void flash_combine(const float* __restrict__ PACC,
                                                     const float* __restrict__ PM,
                                                     const float* __restrict__ PL,
                                                     float* __restrict__ ATT) {
  int gid = blockIdx.x * 4 + (threadIdx.x >> 6);
  int lane = threadIdx.x & 63;
  int n = gid & (NTOK - 1);
  int bh = gid >> 10;
  size_t base = (size_t)bh * 2048 + n;
  float m0 = PM[base], m1 = PM[base + 1024];
  float mx = fmaxf(m0, m1);
  float w0 = __expf(m0 - mx), w1 = __expf(m1 - mx);
  float l = w0 * PL[base] + w1 * PL[base + 1024];
  float a = w0 * PACC[base * 64 + lane] + w1 * PACC[(base + 1024) * 64 + lane];
  int b = bh / NHEAD, h = bh - b * NHEAD;
  unsigned short* AHp = (unsigned short*)ATT;
  unsigned short* ALp = AHp + (size_t)ROWS * CDIM;
  stPlanes(a / l, ((size_t)(b * NTOK + n)) * CDIM + h * HEADD + lane, AHp, ALp);
}

// ---------------------------------------------------------------- output transpose (B,N,C)->(B,C,N)
__global__ __launch_bounds__(256) void out_kernel(const float* __restrict__ X,
                                                  void* __restrict__ out,
                                                  const int* __restrict__ dt) {
  bool isbf = (*dt != 0);
  int idx = blockIdx.x * 256 + threadIdx.x;
  int n = idx & (NTOK - 1);
  int rest = idx >> 10;
  int c = rest % CDIM;
  int b = rest / CDIM;
  float v = X[((size_t)(b * NTOK + n)) * CDIM + c];
  if (isbf)
    ((__hip_bfloat16*)out)[idx] = __float2bfloat16(v);
  else
    ((float*)out)[idx] = v;
}

// ---------------------------------------------------------------- launch
extern "C" void kernel_launch(void* const* d_in, const int* in_sizes, int n_in,
                              void* d_out, int out_size, void* d_ws, size_t ws_size,
                              hipStream_t stream) {
  const void* x       = d_in[0];
  const void* patch_w = d_in[1];
  const void* patch_b = d_in[2];
  const void* ln1_s   = d_in[3];
  const void* ln1_b   = d_in[4];
  const void* qkv_w   = d_in[5];
  const void* offs_w  = d_in[6];
  const void* offs_b  = d_in[7];
  const void* proj_w  = d_in[8];
  const void* proj_b  = d_in[9];
  const void* ln2_s   = d_in[10];
  const void* ln2_b   = d_in[11];
  const void* fc1_w   = d_in[12];
  const void* fc1_b   = d_in[13];
  const void* fc2_w   = d_in[14];
  const void* fc2_b   = d_in[15];

  float* W = (float*)d_ws;
  const size_t XSZ = (size_t)ROWS * CDIM;        // 1,572,864 floats
  float* X    = W;                               // residual stream (f32)
  float* Hb   = W + XSZ;                         // LN out (bf16 hi/lo planes)
  float* ATT  = W + 2 * XSZ;                     // attention out (planes)
  float* QKV  = W + 3 * XSZ;                     // 2048x2304 f32. Also split-K
                                                 // partial base: qkv z=2 spans
                                                 // QKV+BIG (both dead then);
                                                 // proj z=4 / fc2 z=3 likewise.
  float* BIG  = W + 3 * XSZ + (size_t)ROWS * 2304;  // 2048x3072 (fc1 planes / flash PACC)
  float* OFFS = BIG + (size_t)ROWS * 3072;       // 2048x96 f32 (also flash PM/PL region)
  float* PM   = OFFS;
  float* PL   = OFFS + 24 * 4 * NTOK;
  float* Q    = OFFS + 196608;                   // q planes (XSZ floats region)
  int* FLAG   = (int*)(Q + XSZ);

  detect_kernel<<<1, 1, 0, stream>>>(qkv_w, FLAG);

  // patch embed: im2col (planes) -> GEMM (A-stationary: W small, L2-resident)
  im2col_kernel<<<6144, 256, 0, stream>>>(x, QKV, FLAG);
  gemm_kernel<<<dim3(12, 16), 256, 0, stream>>>((const unsigned short*)QKV, 768, patch_w, 0,
                                                patch_b, 0, X, 768, 768, 768, 0, FLAG, nullptr);

  for (int i = 0; i < 6; i++) {
    if (i == 0)
      ln_kernel<<<2048, 256, 0, stream>>>(X, ln1_s, ln1_b, 0, Hb, FLAG);
    bool samp = ((i + 1) % 3 != 0);
    // qkv: W-stationary, split-K=2 (grid 1152 = 4.5 blocks/CU at 24KB LDS).
    // Partials at QKV base (QKV+BIG both dead here); reduce sums in-place and
    // emits q planes on sample layers.
    gemm_kernel<<<dim3(36, 16, 2), 256, 0, stream>>>((const unsigned short*)Hb, 768, qkv_w,
                                                     (size_t)i * 2304 * 768,
                                                     nullptr, 0, QKV, 2304, 2304, 768,
                                                     16, FLAG, QKV);
    reduce_qkv_kernel<<<18432, 256, 0, stream>>>(QKV, samp ? Q : nullptr);
    if (samp) {
      gemm_kernel<<<dim3(2, 16), 256, 0, stream>>>((const unsigned short*)Q, 768, offs_w,
                                                   (size_t)i * 96 * 768,
                                                   offs_b, (size_t)i * 96, OFFS, 96, 96, 768, 0, FLAG, nullptr);
      deform_kernel<<<6144, 256, 0, stream>>>(QKV, OFFS, ATT);
    } else {
      flash_partial<<<768, 256, 0, stream>>>(QKV, BIG, PM, PL);
      flash_combine<<<6144, 256, 0, stream>>>(BIG, PM, PL, ATT);
    }
    // proj: A-stationary, split-K=4 (grid 768 = 3 blocks/CU); partials at QKV
    // base (25.2MB spans QKV + dead BIG head); fused reduce+residual+ln2.
    gemm_kernel<<<dim3(12, 16, 4), 256, 0, stream>>>((const unsigned short*)ATT, 768, proj_w,
                                                     (size_t)i * 768 * 768,
                                                     nullptr, 0, X, 768, 768, 768, 0, FLAG, QKV);
    reduce_ln_kernel<<<2048, 256, 0, stream>>>(QKV, 4, proj_b, (size_t)i * CDIM, X,
                                               ln2_s, ln2_b, (size_t)i * CDIM, Hb, FLAG);
    // fc1: W-stationary, GELU+planes epilogue
    gemm_kernel<<<dim3(48, 16), 256, 0, stream>>>((const unsigned short*)Hb, 768, fc1_w,
                                                  (size_t)i * 3072 * 768,
                                                  fc1_b, (size_t)i * 3072, BIG, 3072, 3072, 768, 22, FLAG, nullptr);
    // fc2: A-stationary, split-K=3; partials in QKV region (dead)
    gemm_kernel<<<dim3(12, 16, 3), 256, 0, stream>>>((const unsigned short*)BIG, 3072, fc2_w,
                                                     (size_t)i * 768 * 3072,
                                                     nullptr, 0, X, 768, 768, 3072, 0, FLAG, QKV);
    if (i < 5)
      reduce_ln_kernel<<<2048, 256, 0, stream>>>(QKV, 3, fc2_b, (size_t)i * CDIM, X,
                                                 ln1_s, ln1_b, (size_t)(i + 1) * CDIM, Hb, FLAG);
    else
      reduce_kernel<<<6144, 256, 0, stream>>>(QKV, 3, fc2_b, (size_t)i * CDIM, X, 1, FLAG);
  }

  out_kernel<<<6144, 256, 0, stream>>>(X, d_out, FLAG);
}

// Round 17
// 1382.881 us; speedup vs baseline: 1.1508x; 1.1508x over previous
//
#include <hip/hip_runtime.h>
#include <hip/hip_bf16.h>
#include <math.h>

// Problem constants
#define NTOK 1024          // Hp*Wp = 32*32
#define CDIM 768
#define BDIM 2
#define ROWS (BDIM*NTOK)   // 2048
#define NHEAD 12
#define HEADD 64
#define SCALE 0.125f       // 64^-0.5

typedef __attribute__((ext_vector_type(8))) __bf16 bfx8;
typedef __attribute__((ext_vector_type(4))) float f32x4;
typedef __attribute__((ext_vector_type(8))) unsigned short u16x8;
typedef __attribute__((ext_vector_type(4))) unsigned short u16x4;

__device__ __forceinline__ float us2f(unsigned short u) {
  return __uint_as_float(((unsigned int)u) << 16);
}
__device__ __forceinline__ unsigned short f2bfu(float v) {
  union { __bf16 b; unsigned short u; } c; c.b = (__bf16)v; return c.u;
}
// dtype-flexible scalar load at ELEMENT index i: isbf ? bf16[i] : f32[i]
__device__ __forceinline__ float ldP(const void* p, size_t i, bool isbf) {
  return isbf ? us2f(((const unsigned short*)p)[i]) : ((const float*)p)[i];
}
// split f32 -> bf16 hi + lo planes
__device__ __forceinline__ void stPlanes(float v, size_t idx,
                                         unsigned short* hp, unsigned short* lp) {
  unsigned short h = f2bfu(v);
  hp[idx] = h;
  lp[idx] = f2bfu(v - us2f(h));
}

__device__ __forceinline__ float waveSum(float v) {
#pragma unroll
  for (int off = 32; off; off >>= 1) v += __shfl_xor(v, off, 64);
  return v;
}

// ---------------------------------------------------------------- dtype detector
// bf16 buffer of 0.02-scale gaussians: ~256/256 halfwords have sane exponent.
// f32 buffer: only odd halfwords do (~152/256 expected). Threshold 220 (≈15σ).
__global__ void detect_kernel(const void* __restrict__ probe, int* __restrict__ flag) {
  const unsigned short* u = (const unsigned short*)probe;
  int plaus = 0;
  for (int i = 0; i < 256; i++) {
    int e = (u[i] >> 7) & 0xFF;
    if (e >= 0x60 && e <= 0x8F) plaus++;
  }
  *flag = (plaus >= 220) ? 1 : 0;
}

// ---------------------------------------------------------------- im2col (plane output)
__global__ __launch_bounds__(256) void im2col_kernel(const void* __restrict__ x,
                                                     float* __restrict__ col,
                                                     const int* __restrict__ dt) {
  bool isbf = (*dt != 0);
  int idx = blockIdx.x * 256 + threadIdx.x;     // < 2048*768
  int k = idx % 768;
  int row = idx / 768;
  int n = row & (NTOK - 1);
  int b = row >> 10;
  int ci = k >> 8;
  int rem = k & 255;
  int py = rem >> 4, px = rem & 15;
  int hp = n >> 5, wp = n & 31;
  int iy = hp * 16 + py, ix = wp * 16 + px;
  size_t xi = (((size_t)(b * 3 + ci) * 512) + iy) * 512 + ix;
  float v = ldP(x, xi, isbf);
  unsigned short* colH = (unsigned short*)col;
  unsigned short* colL = colH + (size_t)ROWS * CDIM;
  stPlanes(v, idx, colH, colL);
}

// ---------------------------------------------------------------- GEMM (MFMA, both dtypes)
// Y[m,n](ldy) (+)= A[m,k] @ W[wOff + n, k]^T + bias[bOff + n]
// A always bf16 hi/lo planes (AH base; AL = AH + ROWS*lda elems).
// isbf: W native bf16 -> 2 products. else: W f32, split in staging -> 3 products.
// Tile: M=128 x N=64, BK=64, 4 waves. LDS 48KB: AH@0(16K) AL@16K WH@32K(8K)
// WL@40K(8K). Row stride 128B = bank period -> per-row 16B-unit swizzle
// phys = u ^ (row&7) (global-source pre-swizzle lu; frag reads px 2-way free).
// This is the session's best-measured GEMM template (r10, 1389.5 us total).
// Falsified levers (r9-r16): conversion hoisting, prefetch placement, MFMA
// halving, cache orientation, global_load_lds, occupancy via LDS/split-K --
// the ~50us/dispatch is the 2-barrier template's structural floor here.
// XCD-chunked bijective block swizzle; split-K via gridDim.z -> f32 partials.
// flags: bit0 residual add, bit1 exact GELU, bit2 plane output,
//        bit3 also write q hi/lo planes (n<768) to Ypart (qkv+cvtq fusion)
__global__ __launch_bounds__(256) void gemm_kernel(
    const unsigned short* __restrict__ Aplanes, int lda,
    const void* __restrict__ Wraw, size_t wOff,
    const void* __restrict__ bias, size_t bOff,
    void* __restrict__ Yreg, int ldy,
    int Nout, int K, int flags, const int* __restrict__ dt,
    float* __restrict__ Ypart) {
  bool isbf = (*dt != 0);
  __shared__ __align__(16) unsigned char sm[49152];
  int tid = threadIdx.x;
  // XCD-chunked bijective swizzle (m204)
  int nwg = gridDim.x * gridDim.y;
  int orig = blockIdx.x + gridDim.x * blockIdx.y;
  int qq = nwg >> 3, rr = nwg & 7;
  int xcd = orig & 7, loc = orig >> 3;
  int wgid = (xcd < rr ? xcd * (qq + 1) : rr * (qq + 1) + (xcd - rr) * qq) + loc;
  int nbase = (wgid % gridDim.x) * 64;
  int mbase = (wgid / gridDim.x) * 128;
  // split-K range
  int KS = K / gridDim.z;
  int kb = blockIdx.z * KS;

  int lane = tid & 63, w = tid >> 6;
  int lr = lane & 15, lg = lane >> 4;

  const unsigned short* AH = Aplanes;
  const unsigned short* AL = AH + (size_t)ROWS * lda;

  // staging roles: thread covers rows r0+32p (A: p=0..3, W: p=0..1)
  int r0 = tid >> 3;
  int lu = (tid & 7) ^ (r0 & 7);                 // pre-swizzled global 16B unit
  size_t gA = (size_t)(mbase + r0) * lda + lu * 8;
  size_t aStep = (size_t)32 * lda;
  int wrow0 = nbase + r0;      if (wrow0 > Nout - 1) wrow0 = Nout - 1;
  int wrow1 = nbase + r0 + 32; if (wrow1 > Nout - 1) wrow1 = Nout - 1;
  size_t gW0 = (size_t)wrow0 * K + lu * 8;
  size_t gW1 = (size_t)wrow1 * K + lu * 8;
  int wr = tid * 16;                             // linear LDS write base

  f32x4 acc[2][4];
#pragma unroll
  for (int i = 0; i < 2; i++)
#pragma unroll
    for (int j = 0; j < 4; j++) acc[i][j] = f32x4{0.f, 0.f, 0.f, 0.f};

  int px0 = (lg ^ (lr & 7)) * 16;                // frag unit bytes, k-slice 0
  int px1 = ((4 | lg) ^ (lr & 7)) * 16;          // k-slice 1
  int rbA = (w * 32 + lr) * 128;                 // A byte row offset, mf=0

  if (isbf) {
    const unsigned short* Wb = (const unsigned short*)Wraw + wOff;
    u16x8 rAh[4], rAl[4], rW0v, rW1v;
#pragma unroll
    for (int p = 0; p < 4; p++) {
      rAh[p] = *(const u16x8*)(AH + gA + p * aStep + kb);
      rAl[p] = *(const u16x8*)(AL + gA + p * aStep + kb);
    }
    rW0v = *(const u16x8*)(Wb + gW0 + kb);
    rW1v = *(const u16x8*)(Wb + gW1 + kb);
    for (int k0 = kb; k0 < kb + KS; k0 += 64) {
      __syncthreads();
#pragma unroll
      for (int p = 0; p < 4; p++) {
        *(u16x8*)(sm + p * 4096 + wr) = rAh[p];
        *(u16x8*)(sm + 16384 + p * 4096 + wr) = rAl[p];
      }
      *(u16x8*)(sm + 32768 + wr) = rW0v;
      *(u16x8*)(sm + 36864 + wr) = rW1v;
      int k1 = k0 + 64;
      if (k1 < kb + KS) {                        // prefetch: hides under MFMA
#pragma unroll
        for (int p = 0; p < 4; p++) {
          rAh[p] = *(const u16x8*)(AH + gA + p * aStep + k1);
          rAl[p] = *(const u16x8*)(AL + gA + p * aStep + k1);
        }
        rW0v = *(const u16x8*)(Wb + gW0 + k1);
        rW1v = *(const u16x8*)(Wb + gW1 + k1);
      }
      __syncthreads();
#pragma unroll
      for (int s = 0; s < 2; s++) {
        int px = s ? px1 : px0;
        bfx8 ah0 = *(const bfx8*)(sm + rbA + px);
        bfx8 ah1 = *(const bfx8*)(sm + rbA + 2048 + px);
        bfx8 al0 = *(const bfx8*)(sm + 16384 + rbA + px);
        bfx8 al1 = *(const bfx8*)(sm + 16384 + rbA + 2048 + px);
#pragma unroll
        for (int nf = 0; nf < 4; nf++) {
          bfx8 wh = *(const bfx8*)(sm + 32768 + (nf * 16 + lr) * 128 + px);
          acc[0][nf] = __builtin_amdgcn_mfma_f32_16x16x32_bf16(ah0, wh, acc[0][nf], 0, 0, 0);
          acc[0][nf] = __builtin_amdgcn_mfma_f32_16x16x32_bf16(al0, wh, acc[0][nf], 0, 0, 0);
          acc[1][nf] = __builtin_amdgcn_mfma_f32_16x16x32_bf16(ah1, wh, acc[1][nf], 0, 0, 0);
          acc[1][nf] = __builtin_amdgcn_mfma_f32_16x16x32_bf16(al1, wh, acc[1][nf], 0, 0, 0);
        }
      }
    }
  } else {
    const float* Wf = (const float*)Wraw + wOff;
    u16x8 rAh[4], rAl[4];
    float4 rWa[2], rWb[2];
#pragma unroll
    for (int p = 0; p < 4; p++) {
      rAh[p] = *(const u16x8*)(AH + gA + p * aStep + kb);
      rAl[p] = *(const u16x8*)(AL + gA + p * aStep + kb);
    }
    rWa[0] = *(const float4*)(Wf + gW0 + kb);
    rWb[0] = *(const float4*)(Wf + gW0 + kb + 4);
    rWa[1] = *(const float4*)(Wf + gW1 + kb);
    rWb[1] = *(const float4*)(Wf + gW1 + kb + 4);
    for (int k0 = kb; k0 < kb + KS; k0 += 64) {
      __syncthreads();
#pragma unroll
      for (int p = 0; p < 4; p++) {
        *(u16x8*)(sm + p * 4096 + wr) = rAh[p];
        *(u16x8*)(sm + 16384 + p * 4096 + wr) = rAl[p];
      }
#pragma unroll
      for (int p = 0; p < 2; p++) {
        float wv[8] = {rWa[p].x, rWa[p].y, rWa[p].z, rWa[p].w,
                       rWb[p].x, rWb[p].y, rWb[p].z, rWb[p].w};
        u16x8 wh8, wl8;
#pragma unroll
        for (int i = 0; i < 8; i++) {
          unsigned short h = f2bfu(wv[i]);
          wh8[i] = h;
          wl8[i] = f2bfu(wv[i] - us2f(h));
        }
        *(u16x8*)(sm + 32768 + p * 4096 + wr) = wh8;
        *(u16x8*)(sm + 40960 + p * 4096 + wr) = wl8;
      }
      int k1 = k0 + 64;
      if (k1 < kb + KS) {
#pragma unroll
        for (int p = 0; p < 4; p++) {
          rAh[p] = *(const u16x8*)(AH + gA + p * aStep + k1);
          rAl[p] = *(const u16x8*)(AL + gA + p * aStep + k1);
        }
        rWa[0] = *(const float4*)(Wf + gW0 + k1);
        rWb[0] = *(const float4*)(Wf + gW0 + k1 + 4);
        rWa[1] = *(const float4*)(Wf + gW1 + k1);
        rWb[1] = *(const float4*)(Wf + gW1 + k1 + 4);
      }
      __syncthreads();
#pragma unroll
      for (int s = 0; s < 2; s++) {
        int px = s ? px1 : px0;
        bfx8 ah0 = *(const bfx8*)(sm + rbA + px);
        bfx8 ah1 = *(const bfx8*)(sm + rbA + 2048 + px);
        bfx8 al0 = *(const bfx8*)(sm + 16384 + rbA + px);
        bfx8 al1 = *(const bfx8*)(sm + 16384 + rbA + 2048 + px);
#pragma unroll
        for (int nf = 0; nf < 4; nf++) {
          int rn = (nf * 16 + lr) * 128 + px;
          bfx8 wh = *(const bfx8*)(sm + 32768 + rn);
          bfx8 wl = *(const bfx8*)(sm + 40960 + rn);
          acc[0][nf] = __builtin_amdgcn_mfma_f32_16x16x32_bf16(ah0, wh, acc[0][nf], 0, 0, 0);
          acc[0][nf] = __builtin_amdgcn_mfma_f32_16x16x32_bf16(al0, wh, acc[0][nf], 0, 0, 0);
          acc[0][nf] = __builtin_amdgcn_mfma_f32_16x16x32_bf16(ah0, wl, acc[0][nf], 0, 0, 0);
          acc[1][nf] = __builtin_amdgcn_mfma_f32_16x16x32_bf16(ah1, wh, acc[1][nf], 0, 0, 0);
          acc[1][nf] = __builtin_amdgcn_mfma_f32_16x16x32_bf16(al1, wh, acc[1][nf], 0, 0, 0);
          acc[1][nf] = __builtin_amdgcn_mfma_f32_16x16x32_bf16(ah1, wl, acc[1][nf], 0, 0, 0);
        }
      }
    }
  }

  // ---- split-K partial epilogue: raw f32, no bias/act (reduce combines)
  if (gridDim.z > 1) {
    float* Pp = Ypart + (size_t)blockIdx.z * ((size_t)ROWS * ldy);
#pragma unroll
    for (int mf = 0; mf < 2; mf++)
#pragma unroll
      for (int nf = 0; nf < 4; nf++) {
        int n = nbase + nf * 16 + lr;
        if (n < Nout) {
#pragma unroll
          for (int r = 0; r < 4; r++) {
            int m = mbase + w * 32 + mf * 16 + lg * 4 + r;
            Pp[(size_t)m * ldy + n] = acc[mf][nf][r];
          }
        }
      }
    return;
  }

  // epilogue: D[row=(lane>>4)*4+r][col=lane&15] per 16x16 frag (verified layout)
  bool pOut = (flags & 4) != 0;
  bool qOut = (flags & 8) != 0;
  unsigned short* YH = (unsigned short*)Yreg;
  unsigned short* YL = YH + (size_t)ROWS * ldy;
  unsigned short* QH = (unsigned short*)Ypart;
  unsigned short* QL = QH + (size_t)ROWS * 768;
#pragma unroll
  for (int mf = 0; mf < 2; mf++) {
#pragma unroll
    for (int nf = 0; nf < 4; nf++) {
      int n = nbase + nf * 16 + lr;
      if (n < Nout) {
        float bv = bias ? ldP(bias, bOff + n, isbf) : 0.f;
#pragma unroll
        for (int r = 0; r < 4; r++) {
          int m = mbase + w * 32 + mf * 16 + lg * 4 + r;
          float v = acc[mf][nf][r] + bv;
          if (flags & 2) v = 0.5f * v * (1.0f + erff(v * 0.70710678118654752f));
          size_t yi = (size_t)m * ldy + n;
          if (pOut) {
            unsigned short h = f2bfu(v);
            YH[yi] = h;
            YL[yi] = f2bfu(v - us2f(h));
          } else {
            float* yp = (float*)Yreg + yi;
            if (flags & 1) v += *yp;
            *yp = v;
            if (qOut && n < 768) stPlanes(v, (size_t)m * 768 + n, QH, QL);
          }
        }
      }
    }
  }
}

// ---------------------------------------------------------------- split-K reduce (plain)
__global__ __launch_bounds__(256) void reduce_kernel(const float* __restrict__ PART,
                                                     int nsplit,
                                                     const void* __restrict__ bias,
                                                     size_t bOff,
                                                     float* __restrict__ X,
                                                     int resid,
                                                     const int* __restrict__ dt) {
  bool isbf = (*dt != 0);
  int idx = blockIdx.x * 256 + threadIdx.x;   // < 2048*768
  int n = idx % 768;
  float v = bias ? ldP(bias, bOff + n, isbf) : 0.f;
  const size_t XS = (size_t)ROWS * 768;
  for (int z = 0; z < nsplit; z++) v += PART[(size_t)z * XS + idx];
  X[idx] = resid ? (X[idx] + v) : v;
}

// ---------------------------------------------------------------- fused split-K reduce + residual + LayerNorm
__global__ __launch_bounds__(256) void reduce_ln_kernel(
    const float* __restrict__ PART, int nsplit,
    const void* __restrict__ bias, size_t bOff,
    float* __restrict__ X,
    const void* __restrict__ gs, const void* __restrict__ gb, size_t gOff,
    float* __restrict__ H, const int* __restrict__ dt) {
  bool isbf = (*dt != 0);
  int row = blockIdx.x;
  int tid = threadIdx.x;
  const size_t XS = (size_t)ROWS * 768;
  size_t rb = (size_t)row * CDIM;
  float v0, v1, v2;
  {
    float s0 = X[rb + tid]       + ldP(bias, bOff + tid, isbf);
    float s1 = X[rb + tid + 256] + ldP(bias, bOff + tid + 256, isbf);
    float s2 = X[rb + tid + 512] + ldP(bias, bOff + tid + 512, isbf);
    for (int z = 0; z < nsplit; z++) {
      const float* pz = PART + (size_t)z * XS + rb;
      s0 += pz[tid]; s1 += pz[tid + 256]; s2 += pz[tid + 512];
    }
    v0 = s0; v1 = s1; v2 = s2;
    X[rb + tid] = s0; X[rb + tid + 256] = s1; X[rb + tid + 512] = s2;
  }
  float sum = waveSum(v0 + v1 + v2);
  __shared__ float red[4];
  __shared__ float statMu;
  __shared__ float statRs;
  int wid = tid >> 6, lane = tid & 63;
  if (lane == 0) red[wid] = sum;
  __syncthreads();
  if (tid == 0) statMu = (red[0] + red[1] + red[2] + red[3]) * (1.0f / 768.0f);
  __syncthreads();
  float mu = statMu;
  float d0 = v0 - mu, d1 = v1 - mu, d2 = v2 - mu;
  float sq = waveSum(d0 * d0 + d1 * d1 + d2 * d2);
  if (lane == 0) red[wid] = sq;
  __syncthreads();
  if (tid == 0)
    statRs = rsqrtf((red[0] + red[1] + red[2] + red[3]) * (1.0f / 768.0f) + 1e-6f);
  __syncthreads();
  float rs = statRs;
  unsigned short* HH = (unsigned short*)H;
  unsigned short* HL = HH + (size_t)ROWS * CDIM;
  stPlanes(d0 * rs * ldP(gs, gOff + tid, isbf)       + ldP(gb, gOff + tid, isbf),       rb + tid, HH, HL);
  stPlanes(d1 * rs * ldP(gs, gOff + tid + 256, isbf) + ldP(gb, gOff + tid + 256, isbf), rb + tid + 256, HH, HL);
  stPlanes(d2 * rs * ldP(gs, gOff + tid + 512, isbf) + ldP(gb, gOff + tid + 512, isbf), rb + tid + 512, HH, HL);
}

// ---------------------------------------------------------------- LayerNorm (plane output)
__global__ __launch_bounds__(256) void ln_kernel(const float* __restrict__ X,
                                                 const void* __restrict__ gs,
                                                 const void* __restrict__ gb,
                                                 size_t gOff,
                                                 float* __restrict__ H,
                                                 const int* __restrict__ dt) {
  bool isbf = (*dt != 0);
  int row = blockIdx.x;
  int tid = threadIdx.x;
  const float* xr = X + (size_t)row * CDIM;
  float v0 = xr[tid], v1 = xr[tid + 256], v2 = xr[tid + 512];
  float sum = waveSum(v0 + v1 + v2);
  __shared__ float red[4];
  __shared__ float statMu;
  __shared__ float statRs;
  int wid = tid >> 6, lane = tid & 63;
  if (lane == 0) red[wid] = sum;
  __syncthreads();
  if (tid == 0) statMu = (red[0] + red[1] + red[2] + red[3]) * (1.0f / 768.0f);
  __syncthreads();
  float mu = statMu;
  float d0 = v0 - mu, d1 = v1 - mu, d2 = v2 - mu;
  float sq = waveSum(d0 * d0 + d1 * d1 + d2 * d2);
  if (lane == 0) red[wid] = sq;
  __syncthreads();
  if (tid == 0)
    statRs = rsqrtf((red[0] + red[1] + red[2] + red[3]) * (1.0f / 768.0f) + 1e-6f);
  __syncthreads();
  float rs = statRs;
  unsigned short* HH = (unsigned short*)H;
  unsigned short* HL = HH + (size_t)ROWS * CDIM;
  size_t rb = (size_t)row * CDIM;
  stPlanes(d0 * rs * ldP(gs, gOff + tid, isbf)       + ldP(gb, gOff + tid, isbf),       rb + tid, HH, HL);
  stPlanes(d1 * rs * ldP(gs, gOff + tid + 256, isbf) + ldP(gb, gOff + tid + 256, isbf), rb + tid + 256, HH, HL);
  stPlanes(d2 * rs * ldP(gs, gOff + tid + 512, isbf) + ldP(gb, gOff + tid + 512, isbf), rb + tid + 512, HH, HL);
}

// ---------------------------------------------------------------- deformable attention (plane output)
__global__ __launch_bounds__(256) void deform_kernel(const float* __restrict__ QKV,
                                                     const float* __restrict__ OFFS,
                                                     float* __restrict__ ATT) {
  int gid = blockIdx.x * 4 + (threadIdx.x >> 6);   // < 24576 = 2048*12
  int lane = threadIdx.x & 63;
  int h = gid % NHEAD;
  int bn = gid / NHEAD;          // b*1024 + n
  int n = bn & (NTOK - 1);
  int b = bn >> 10;
  int hp = n >> 5, wp = n & 31;

  float qd = QKV[(size_t)bn * 2304 + h * HEADD + lane];
  const float* orow = OFFS + (size_t)bn * 96 + h * 8;

  float sv[4], sc[4];
#pragma unroll
  for (int p = 0; p < 4; p++) {
    float ox = orow[p * 2 + 0];
    float oy = orow[p * 2 + 1];
    float xx = (float)wp + ox;
    float yy = (float)hp + oy;
    float x0f = floorf(xx), y0f = floorf(yy);
    int x0 = (int)x0f, y0 = (int)y0f;
    float wx = xx - x0f, wy = yy - y0f;
    int xs[2] = {x0, x0 + 1};
    int ys[2] = {y0, y0 + 1};
    float wxs[2] = {1.f - wx, wx};
    float wys[2] = {1.f - wy, wy};
    float skv = 0.f, svv = 0.f;
#pragma unroll
    for (int cy = 0; cy < 2; cy++) {
#pragma unroll
      for (int cx = 0; cx < 2; cx++) {
        int yi = ys[cy], xi = xs[cx];
        if (yi >= 0 && yi < 32 && xi >= 0 && xi < 32) {
          const float* kp = QKV + ((size_t)(b * NTOK + (yi << 5) + xi)) * 2304 + CDIM + h * HEADD + lane;
          float w = wys[cy] * wxs[cx];
          skv += w * kp[0];
          svv += w * kp[CDIM];
        }
      }
    }
    sv[p] = svv;
    sc[p] = waveSum(qd * skv) * SCALE;
  }
  float mx = fmaxf(fmaxf(sc[0], sc[1]), fmaxf(sc[2], sc[3]));
  float e0 = expf(sc[0] - mx), e1 = expf(sc[1] - mx), e2 = expf(sc[2] - mx), e3 = expf(sc[3] - mx);
  float l = e0 + e1 + e2 + e3;
  float od = (e0 * sv[0] + e1 * sv[1] + e2 * sv[2] + e3 * sv[3]) / l;
  unsigned short* AHp = (unsigned short*)ATT;
  unsigned short* ALp = AHp + (size_t)ROWS * CDIM;
  stPlanes(od, (size_t)bn * CDIM + h * HEADD + lane, AHp, ALp);
}

// ---------------------------------------------------------------- full attention (MFMA flash partial + combine)
__global__ __launch_bounds__(256) void flash_partial(const float* __restrict__ QKV,
                                                     float* __restrict__ PACC,
                                                     float* __restrict__ PM,
                                                     float* __restrict__ PL) {
  int bid = blockIdx.x;                 // ((b*12+h)*2 + kc)*16 + qb
  int qb = bid & 15;
  int kc = (bid >> 4) & 1;
  int bh = bid >> 5;                    // 0..23 = b*12 + h
  int h = bh % NHEAD;
  int b = bh / NHEAD;
  int tid = threadIdx.x;
  int lane = tid & 63, wq = tid >> 6;
  int lr = lane & 15, lg = lane >> 4;

  __shared__ __align__(16) unsigned short KH[64 * 72];
  __shared__ __align__(16) unsigned short KL[64 * 72];
  __shared__ __align__(16) unsigned short VTH[64 * 64];
  __shared__ __align__(16) unsigned short VTL[64 * 64];
  __shared__ __align__(16) unsigned short PH[4 * 16 * 64];
  __shared__ __align__(16) unsigned short PL_[4 * 16 * 64];

  const float* base = QKV + (size_t)b * NTOK * 2304;

  int qrow = qb * 64 + wq * 16 + lr;
  bfx8 qh[2], ql[2];
  {
    const float* qp = base + (size_t)qrow * 2304 + h * HEADD;
#pragma unroll
    for (int ks = 0; ks < 2; ks++) {
      float4 a0 = *(const float4*)(qp + ks * 32 + lg * 8);
      float4 a1 = *(const float4*)(qp + ks * 32 + lg * 8 + 4);
      float vv[8] = {a0.x, a0.y, a0.z, a0.w, a1.x, a1.y, a1.z, a1.w};
#pragma unroll
      for (int i = 0; i < 8; i++) {
        float sv = vv[i] * SCALE;
        __bf16 hh = (__bf16)sv;
        qh[ks][i] = hh;
        ql[ks][i] = (__bf16)(sv - (float)hh);
      }
    }
  }

  f32x4 oacc[4];
#pragma unroll
  for (int i = 0; i < 4; i++) oacc[i] = f32x4{0.f, 0.f, 0.f, 0.f};
  float mrun = -1e30f, l = 0.f;

  int srow = tid >> 2, su = tid & 3;
  const float* kgp = base + (size_t)srow * 2304 + CDIM + h * HEADD + su * 16;
  int vk = 4 * (tid & 15);
  int vd = 4 * (tid >> 4);

  float4 kr[4];
  float vrf[4][4];
  {
    int k0 = kc * 512;
#pragma unroll
    for (int c = 0; c < 4; c++)
      kr[c] = *(const float4*)(kgp + (size_t)k0 * 2304 + c * 4);
#pragma unroll
    for (int i = 0; i < 4; i++) {
      float4 t = *(const float4*)(base + (size_t)(k0 + vk + i) * 2304 + 2 * CDIM + h * HEADD + vd);
      vrf[i][0] = t.x; vrf[i][1] = t.y; vrf[i][2] = t.z; vrf[i][3] = t.w;
    }
  }

  for (int t = 0; t < 8; t++) {
    __syncthreads();
    {
      int e = srow * 72 + su * 16;
#pragma unroll
      for (int c2 = 0; c2 < 2; c2++) {
        float vv[8] = {kr[2 * c2].x, kr[2 * c2].y, kr[2 * c2].z, kr[2 * c2].w,
                       kr[2 * c2 + 1].x, kr[2 * c2 + 1].y, kr[2 * c2 + 1].z, kr[2 * c2 + 1].w};
        u16x8 hv, lv;
#pragma unroll
        for (int i = 0; i < 8; i++) {
          unsigned short hu = f2bfu(vv[i]);
          hv[i] = hu;
          lv[i] = f2bfu(vv[i] - us2f(hu));
        }
        *(u16x8*)&KH[e + c2 * 8] = hv;
        *(u16x8*)&KL[e + c2 * 8] = lv;
      }
    }
#pragma unroll
    for (int j = 0; j < 4; j++) {
      int d = vd + j;
      int off = d * 64 + (((vk >> 3) ^ (d & 7)) << 3) + (vk & 7);
      u16x4 hv, lv;
#pragma unroll
      for (int i = 0; i < 4; i++) {
        unsigned short hu = f2bfu(vrf[i][j]);
        hv[i] = hu;
        lv[i] = f2bfu(vrf[i][j] - us2f(hu));
      }
      *(u16x4*)&VTH[off] = hv;
      *(u16x4*)&VTL[off] = lv;
    }
    __syncthreads();
    if (t < 7) {
      int k0 = kc * 512 + (t + 1) * 64;
#pragma unroll
      for (int c = 0; c < 4; c++)
        kr[c] = *(const float4*)(kgp + (size_t)k0 * 2304 + c * 4);
#pragma unroll
      for (int i = 0; i < 4; i++) {
        float4 tv = *(const float4*)(base + (size_t)(k0 + vk + i) * 2304 + 2 * CDIM + h * HEADD + vd);
        vrf[i][0] = tv.x; vrf[i][1] = tv.y; vrf[i][2] = tv.z; vrf[i][3] = tv.w;
      }
    }

    f32x4 sAcc[4];
#pragma unroll
    for (int mf = 0; mf < 4; mf++) sAcc[mf] = f32x4{0.f, 0.f, 0.f, 0.f};
#pragma unroll
    for (int mf = 0; mf < 4; mf++) {
      int R = mf * 16 + lr;
#pragma unroll
      for (int ks = 0; ks < 2; ks++) {
        int e = R * 72 + (4 * ks + lg) * 8;
        bfx8 kh = *(const bfx8*)&KH[e];
        bfx8 kl = *(const bfx8*)&KL[e];
        sAcc[mf] = __builtin_amdgcn_mfma_f32_16x16x32_bf16(kh, qh[ks], sAcc[mf], 0, 0, 0);
        sAcc[mf] = __builtin_amdgcn_mfma_f32_16x16x32_bf16(kl, qh[ks], sAcc[mf], 0, 0, 0);
        sAcc[mf] = __builtin_amdgcn_mfma_f32_16x16x32_bf16(kh, ql[ks], sAcc[mf], 0, 0, 0);
      }
    }

    float pmax = sAcc[0][0];
#pragma unroll
    for (int mf = 0; mf < 4; mf++)
#pragma unroll
      for (int r = 0; r < 4; r++) pmax = fmaxf(pmax, sAcc[mf][r]);
    pmax = fmaxf(pmax, __shfl_xor(pmax, 16, 64));
    pmax = fmaxf(pmax, __shfl_xor(pmax, 32, 64));
    if (!__all(pmax - mrun <= 8.f)) {
      float mnew = fmaxf(mrun, pmax);
      float alpha = __expf(mrun - mnew);
      l *= alpha;
#pragma unroll
      for (int r = 0; r < 4; r++) {
        float ar = __shfl(alpha, 4 * lg + r, 64);
#pragma unroll
        for (int nf = 0; nf < 4; nf++) oacc[nf][r] *= ar;
      }
      mrun = mnew;
    }
    float p[4][4];
    float lsum = 0.f;
#pragma unroll
    for (int mf = 0; mf < 4; mf++)
#pragma unroll
      for (int r = 0; r < 4; r++) {
        float pv = __expf(sAcc[mf][r] - mrun);
        p[mf][r] = pv;
        lsum += pv;
      }
    lsum += __shfl_xor(lsum, 16, 64);
    lsum += __shfl_xor(lsum, 32, 64);
    l += lsum;

#pragma unroll
    for (int mf = 0; mf < 4; mf++) {
      int u = 2 * mf + (lg >> 1);
      int off = wq * 1024 + lr * 64 + ((u ^ (lr & 7)) << 3) + (lg & 1) * 4;
      u16x4 hv, lv;
#pragma unroll
      for (int r = 0; r < 4; r++) {
        unsigned short hu = f2bfu(p[mf][r]);
        hv[r] = hu;
        lv[r] = f2bfu(p[mf][r] - us2f(hu));
      }
      *(u16x4*)&PH[off] = hv;
      *(u16x4*)&PL_[off] = lv;
    }
    asm volatile("s_waitcnt lgkmcnt(0)" ::: "memory");
    __builtin_amdgcn_sched_barrier(0);

#pragma unroll
    for (int ks = 0; ks < 2; ks++) {
      int poff = wq * 1024 + lr * 64 + (((4 * ks + lg) ^ (lr & 7)) << 3);
      bfx8 pa_h = *(const bfx8*)&PH[poff];
      bfx8 pa_l = *(const bfx8*)&PL_[poff];
#pragma unroll
      for (int nf = 0; nf < 4; nf++) {
        int d = nf * 16 + lr;
        int voff = d * 64 + (((4 * ks + lg) ^ (d & 7)) << 3);
        bfx8 vb_h = *(const bfx8*)&VTH[voff];
        bfx8 vb_l = *(const bfx8*)&VTL[voff];
        oacc[nf] = __builtin_amdgcn_mfma_f32_16x16x32_bf16(pa_h, vb_h, oacc[nf], 0, 0, 0);
        oacc[nf] = __builtin_amdgcn_mfma_f32_16x16x32_bf16(pa_l, vb_h, oacc[nf], 0, 0, 0);
        oacc[nf] = __builtin_amdgcn_mfma_f32_16x16x32_bf16(pa_h, vb_l, oacc[nf], 0, 0, 0);
      }
    }
  }

  size_t idxbase = (size_t)(bh * 2 + kc) * NTOK;
  if (lane < 16) {
    PM[idxbase + qrow] = mrun;
    PL[idxbase + qrow] = l;
  }
#pragma unroll
  for (int r = 0; r < 4; r++) {
    int qg = qb * 64 + wq * 16 + 4 * lg + r;
    float* ap = PACC + (idxbase + qg) * 64;
#pragma unroll
    for (int nf = 0; nf < 4; nf++) ap[nf * 16 + lr] = oacc[nf][r];
  }
}

__global__ __launch_bounds__(256) void flash_combine(const float* __restrict__ PACC,
                                                     const float* __restrict__ PM,
                                                     const float* __restrict__ PL,
                                                     float* __restrict__ ATT) {
  int gid = blockIdx.x * 4 + (threadIdx.x >> 6);
  int lane = threadIdx.x & 63;
  int n = gid & (NTOK - 1);
  int bh = gid >> 10;
  size_t base = (size_t)bh * 2048 + n;
  float m0 = PM[base], m1 = PM[base + 1024];
  float mx = fmaxf(m0, m1);
  float w0 = __expf(m0 - mx), w1 = __expf(m1 - mx);
  float l = w0 * PL[base] + w1 * PL[base + 1024];
  float a = w0 * PACC[base * 64 + lane] + w1 * PACC[(base + 1024) * 64 + lane];
  int b = bh / NHEAD, h = bh - b * NHEAD;
  unsigned short* AHp = (unsigned short*)ATT;
  unsigned short* ALp = AHp + (size_t)ROWS * CDIM;
  stPlanes(a / l, ((size_t)(b * NTOK + n)) * CDIM + h * HEADD + lane, AHp, ALp);
}

// ---------------------------------------------------------------- output transpose (B,N,C)->(B,C,N)
__global__ __launch_bounds__(256) void out_kernel(const float* __restrict__ X,
                                                  void* __restrict__ out,
                                                  const int* __restrict__ dt) {
  bool isbf = (*dt != 0);
  int idx = blockIdx.x * 256 + threadIdx.x;
  int n = idx & (NTOK - 1);
  int rest = idx >> 10;
  int c = rest % CDIM;
  int b = rest / CDIM;
  float v = X[((size_t)(b * NTOK + n)) * CDIM + c];
  if (isbf)
    ((__hip_bfloat16*)out)[idx] = __float2bfloat16(v);
  else
    ((float*)out)[idx] = v;
}

// ---------------------------------------------------------------- launch
extern "C" void kernel_launch(void* const* d_in, const int* in_sizes, int n_in,
                              void* d_out, int out_size, void* d_ws, size_t ws_size,
                              hipStream_t stream) {
  const void* x       = d_in[0];
  const void* patch_w = d_in[1];
  const void* patch_b = d_in[2];
  const void* ln1_s   = d_in[3];
  const void* ln1_b   = d_in[4];
  const void* qkv_w   = d_in[5];
  const void* offs_w  = d_in[6];
  const void* offs_b  = d_in[7];
  const void* proj_w  = d_in[8];
  const void* proj_b  = d_in[9];
  const void* ln2_s   = d_in[10];
  const void* ln2_b   = d_in[11];
  const void* fc1_w   = d_in[12];
  const void* fc1_b   = d_in[13];
  const void* fc2_w   = d_in[14];
  const void* fc2_b   = d_in[15];

  float* W = (float*)d_ws;
  const size_t XSZ = (size_t)ROWS * CDIM;        // 1,572,864 floats
  float* X    = W;                               // residual stream (f32)
  float* Hb   = W + XSZ;                         // LN out (bf16 hi/lo planes)
  float* ATT  = W + 2 * XSZ;                     // attention out (planes)
  float* QKV  = W + 3 * XSZ;                     // 2048x2304 f32; dead after attn ->
                                                 //   reused as split-K partials (3*XSZ)
  float* BIG  = W + 3 * XSZ + (size_t)ROWS * 2304;  // 2048x3072 (fc1 planes / flash PACC)
  float* OFFS = BIG + (size_t)ROWS * 3072;       // 2048x96 f32 (also flash PM/PL region)
  float* PM   = OFFS;
  float* PL   = OFFS + 24 * 4 * NTOK;
  float* Q    = OFFS + 196608;                   // q planes (XSZ floats region)
  int* FLAG   = (int*)(Q + XSZ);

  detect_kernel<<<1, 1, 0, stream>>>(qkv_w, FLAG);

  // patch embed: im2col (planes) -> GEMM
  im2col_kernel<<<6144, 256, 0, stream>>>(x, QKV, FLAG);
  gemm_kernel<<<dim3(12, 16), 256, 0, stream>>>((const unsigned short*)QKV, 768, patch_w, 0,
                                                patch_b, 0, X, 768, 768, 768, 0, FLAG, nullptr);

  for (int i = 0; i < 6; i++) {
    if (i == 0)
      ln_kernel<<<2048, 256, 0, stream>>>(X, ln1_s, ln1_b, 0, Hb, FLAG);
    // (layers 1..5: Hb planes were produced by previous layer's fused fc2 reduce_ln)
    bool samp = ((i + 1) % 3 != 0);
    // qkv; on sample layers also emit q hi/lo planes (flag 8) -> fuses cvtq
    gemm_kernel<<<dim3(36, 16), 256, 0, stream>>>((const unsigned short*)Hb, 768, qkv_w,
                                                  (size_t)i * 2304 * 768,
                                                  nullptr, 0, QKV, 2304, 2304, 768,
                                                  samp ? 8 : 0, FLAG, samp ? Q : nullptr);
    if (samp) {
      gemm_kernel<<<dim3(2, 16), 256, 0, stream>>>((const unsigned short*)Q, 768, offs_w,
                                                   (size_t)i * 96 * 768,
                                                   offs_b, (size_t)i * 96, OFFS, 96, 96, 768, 0, FLAG, nullptr);
      deform_kernel<<<6144, 256, 0, stream>>>(QKV, OFFS, ATT);
    } else {
      flash_partial<<<768, 256, 0, stream>>>(QKV, BIG, PM, PL);
      flash_combine<<<6144, 256, 0, stream>>>(BIG, PM, PL, ATT);
    }
    // proj: split-K=2 into QKV region; fused reduce + residual + ln2 -> Hb planes
    gemm_kernel<<<dim3(12, 16, 2), 256, 0, stream>>>((const unsigned short*)ATT, 768, proj_w,
                                                     (size_t)i * 768 * 768,
                                                     nullptr, 0, X, 768, 768, 768, 0, FLAG, QKV);
    reduce_ln_kernel<<<2048, 256, 0, stream>>>(QKV, 2, proj_b, (size_t)i * CDIM, X,
                                               ln2_s, ln2_b, (size_t)i * CDIM, Hb, FLAG);
    gemm_kernel<<<dim3(48, 16), 256, 0, stream>>>((const unsigned short*)Hb, 768, fc1_w,
                                                  (size_t)i * 3072 * 768,
                                                  fc1_b, (size_t)i * 3072, BIG, 3072, 3072, 768, 6, FLAG, nullptr);
    // fc2: split-K=3 into QKV region; fused reduce + residual + next-layer ln1
    gemm_kernel<<<dim3(12, 16, 3), 256, 0, stream>>>((const unsigned short*)BIG, 3072, fc2_w,
                                                     (size_t)i * 768 * 3072,
                                                     nullptr, 0, X, 768, 768, 3072, 0, FLAG, QKV);
    if (i < 5)
      reduce_ln_kernel<<<2048, 256, 0, stream>>>(QKV, 3, fc2_b, (size_t)i * CDIM, X,
                                                 ln1_s, ln1_b, (size_t)(i + 1) * CDIM, Hb, FLAG);
    else
      reduce_kernel<<<6144, 256, 0, stream>>>(QKV, 3, fc2_b, (size_t)i * CDIM, X, 1, FLAG);
  }

  out_kernel<<<6144, 256, 0, stream>>>(X, d_out, FLAG);
}